// Round 7
// baseline (559.495 us; speedup 1.0000x reference)
//
#include <hip/hip_runtime.h>

#define THREADS 256
#define SPT 2
#define SAMPLES_PER_BLOCK (THREADS * SPT)

// LDS weight layout (dword offsets)
#define OFF_WC 0       // 729
#define OFF_BC 729     // 81
#define OFF_WH 810     // 243
#define OFF_BH 1053    // 27
#define OFF_WM 1080    // 108
#define OFF_BM 1188    // 12
#define OFF_WO 1200    // 16
#define OFF_BO 1216    // 4
#define W_TOTAL 1220

__device__ __forceinline__ float fast_sigmoid(float v) {
    float e = __expf(-v);
    return __builtin_amdgcn_rcpf(1.0f + e);
}

// Weights live in LDS (4.9 KB/block), read as same-address BROADCAST ds_reads
// (conflict-free, pipelinable with fine lgkmcnt(N)) instead of the SGPR-starved
// s_load drain chains that every previous round was serialized on.
__global__ __launch_bounds__(THREADS, 4) void olcnn_kernel(
    const float* __restrict__ x,
    const float* __restrict__ Wc, const float* __restrict__ bc,
    const float* __restrict__ Wh, const float* __restrict__ bh,
    const float* __restrict__ Wm, const float* __restrict__ bm,
    const float* __restrict__ Wo, const float* __restrict__ bo,
    float* __restrict__ out)
{
    __shared__ __align__(16) float w[W_TOTAL];
    const int tid = threadIdx.x;

    // One-time cooperative weight staging (runs once; cost amortized over
    // 512 samples/block).
    for (int i = tid; i < 729; i += THREADS) w[OFF_WC + i] = Wc[i];
    for (int i = tid; i < 81;  i += THREADS) w[OFF_BC + i] = bc[i];
    for (int i = tid; i < 243; i += THREADS) w[OFF_WH + i] = Wh[i];
    for (int i = tid; i < 27;  i += THREADS) w[OFF_BH + i] = bh[i];
    for (int i = tid; i < 108; i += THREADS) w[OFF_WM + i] = Wm[i];
    for (int i = tid; i < 12;  i += THREADS) w[OFF_BM + i] = bm[i];
    for (int i = tid; i < 16;  i += THREADS) w[OFF_WO + i] = Wo[i];
    for (int i = tid; i < 4;   i += THREADS) w[OFF_BO + i] = bo[i];
    __syncthreads();

    const int wave = tid >> 6, lane = tid & 63;
    const int s0 = blockIdx.x * SAMPLES_PER_BLOCK + wave * (64 * SPT) + lane;
    const int s1 = s0 + 64;
    const float* xA = x + s0 * 81;
    const float* xB = x + s1 * 81;

    float res[2][4];

    #pragma unroll
    for (int G = 0; G < 3; ++G) {
        // 27-float chunk per sample; wave footprint contiguous -> lines fully
        // consumed via L1/L3 (x is L3-hot: only 170 MB).
        float c0[27], c1[27];
        #pragma unroll
        for (int j = 0; j < 27; ++j) c0[j] = xA[G * 27 + j];
        #pragma unroll
        for (int j = 0; j < 27; ++j) c1[j] = xB[G * 27 + j];

        float hb0[9], hb1[9];
        #pragma unroll
        for (int j = 0; j < 3; ++j) {            // conv patch g = (G, j)
            const int g = G * 3 + j;
            float ft0[9], ft1[9];
            #pragma unroll
            for (int k = 0; k < 9; ++k) {
                float a0 = w[OFF_BC + g * 9 + k], a1 = a0;
                #pragma unroll
                for (int pr = 0; pr < 3; ++pr)
                    #pragma unroll
                    for (int pc = 0; pc < 3; ++pc) {
                        const float wv = w[OFF_WC + (g * 9 + k) * 9 + pr * 3 + pc];
                        const int ci = pr * 9 + j * 3 + pc;
                        a0 = fmaf(c0[ci], wv, a0);
                        a1 = fmaf(c1[ci], wv, a1);
                    }
                ft0[k] = fast_sigmoid(a0);
                ft1[k] = fast_sigmoid(a1);
            }
            #pragma unroll
            for (int n = 0; n < 3; ++n) {
                float a0 = w[OFF_BH + g * 3 + n], a1 = a0;
                #pragma unroll
                for (int p = 0; p < 9; ++p) {
                    const float wv = w[OFF_WH + (g * 3 + n) * 9 + p];
                    a0 = fmaf(ft0[p], wv, a0);
                    a1 = fmaf(ft1[p], wv, a1);
                }
                hb0[j * 3 + n] = fast_sigmoid(a0);
                hb1[j * 3 + n] = fast_sigmoid(a1);
            }
        }

        float m0[4], m1[4];
        #pragma unroll
        for (int n = 0; n < 4; ++n) {
            float a0 = w[OFF_BM + G * 4 + n], a1 = a0;
            #pragma unroll
            for (int p = 0; p < 9; ++p) {
                const float wv = w[OFF_WM + (G * 4 + n) * 9 + p];
                a0 = fmaf(hb0[p], wv, a0);
                a1 = fmaf(hb1[p], wv, a1);
            }
            m0[n] = fast_sigmoid(a0);
            m1[n] = fast_sigmoid(a1);
        }

        // outputs reading middle group G: c = G, plus c = 3 for G = 0
        {
            float a0 = w[OFF_BO + G], a1 = a0;
            #pragma unroll
            for (int p = 0; p < 4; ++p) {
                const float wv = w[OFF_WO + G * 4 + p];
                a0 = fmaf(m0[p], wv, a0);
                a1 = fmaf(m1[p], wv, a1);
            }
            res[0][G] = a0; res[1][G] = a1;
        }
        if (G == 0) {
            float a0 = w[OFF_BO + 3], a1 = a0;
            #pragma unroll
            for (int p = 0; p < 4; ++p) {
                const float wv = w[OFF_WO + 12 + p];
                a0 = fmaf(m0[p], wv, a0);
                a1 = fmaf(m1[p], wv, a1);
            }
            res[0][3] = a0; res[1][3] = a1;
        }
    }

    float4 o0, o1;
    o0.x = res[0][0]; o0.y = res[0][1]; o0.z = res[0][2]; o0.w = res[0][3];
    o1.x = res[1][0]; o1.y = res[1][1]; o1.z = res[1][2]; o1.w = res[1][3];
    ((float4*)out)[s0] = o0;
    ((float4*)out)[s1] = o1;
}

extern "C" void kernel_launch(void* const* d_in, const int* in_sizes, int n_in,
                              void* d_out, int out_size, void* d_ws, size_t ws_size,
                              hipStream_t stream) {
    const float* x  = (const float*)d_in[0];
    const float* Wc = (const float*)d_in[1];
    const float* bc = (const float*)d_in[2];
    const float* Wh = (const float*)d_in[3];
    const float* bh = (const float*)d_in[4];
    const float* Wm = (const float*)d_in[5];
    const float* bm = (const float*)d_in[6];
    const float* Wo = (const float*)d_in[7];
    const float* bo = (const float*)d_in[8];
    float* out = (float*)d_out;

    const int B = in_sizes[0] / 81;                    // 524288
    const int blocks = B / SAMPLES_PER_BLOCK;          // 1024 (exact)
    olcnn_kernel<<<blocks, THREADS, 0, stream>>>(x, Wc, bc, Wh, bh, Wm, bm,
                                                 Wo, bo, out);
}